// Round 7
// baseline (205.008 us; speedup 1.0000x reference)
//
#include <hip/hip_runtime.h>
#include <stdint.h>

#define NSIG   32768
#define NATOM  512
#define MDIM   64
#define SPAR   5
#define EPS    1e-10

// ---------------- prep: normalize dictionary into fp64 (transposed layout) ---
__global__ __launch_bounds__(512) void prep_kernel(const float* __restrict__ D,
                                                   double* __restrict__ Dt,
                                                   double* __restrict__ nrm2) {
  int n = threadIdx.x;                 // atom 0..511
  double ss = 0.0;
#pragma unroll 8
  for (int c = 0; c < MDIM; ++c) {
    double v = (double)D[c * NATOM + n];
    ss += v * v;
  }
  double norm = sqrt(ss);
  if (norm < 1e-10) norm = 1e-10;
  double s2 = 0.0;
#pragma unroll 8
  for (int c = 0; c < MDIM; ++c) {
    double v = (double)D[c * NATOM + n] / norm;
    Dt[(size_t)c * NATOM + n] = v;
    s2 += v * v;
  }
  nrm2[n] = s2;
}

// ---------------- Gram matrix G = Dn^T Dn (fp64, 512x512) --------------------
__global__ __launch_bounds__(512) void gram_kernel(const double* __restrict__ Dt,
                                                   double* __restrict__ G) {
  int i = blockIdx.x;
  int j = threadIdx.x;
  double s = 0.0;
#pragma unroll 8
  for (int c = 0; c < MDIM; ++c)
    s += Dt[(size_t)c * NATOM + i] * Dt[(size_t)c * NATOM + j];
  G[(size_t)i * NATOM + j] = s;
}

// ---------------- repack: xw[l][c][b] = z_e[b][c][l] (f32) -------------------
__global__ __launch_bounds__(512) void repack_kernel(const float* __restrict__ z_e,
                                                     float* __restrict__ xw) {
  int bid = blockIdx.x;
  int l = ((bid & 7) << 7) | (bid >> 3);
#pragma unroll
  for (int p = 0; p < 4; ++p) {
    int idx = threadIdx.x + p * 512;       // 0..2047 = c*32+b
    xw[(size_t)l * 2048 + idx] = z_e[(size_t)(idx & 31) * 65536 + (size_t)(idx >> 5) * 1024 + l];
  }
}

// key = (|c| truncated to 2^-42, sign bit of c, 511-idx). Monotone for val>=0;
// u64 max == (first-max argmax of |c|, lower idx wins ties) == np semantics
// when masked atoms compete with value 0.
__device__ __forceinline__ unsigned long long pack_key(double val, unsigned int hi_c, int idx) {
  unsigned int khi = (unsigned int)__double2hiint(val);
  unsigned int klo = ((unsigned int)__double2loint(val) & 0xFFFFFC00u)
                   | ((hi_c >> 22) & 0x200u) | (unsigned int)(511 - idx);
  return ((unsigned long long)khi << 32) | klo;
}

// ---------------- main OMP kernel: 16 sigs/block, 4-way atom split -----------
// block = 256 threads = 4 waves; block handles half-token (16 sigs of token l).
// Wave w owns atoms [w*128, w*128+128); lane owns 2 atoms. cor[2][16] in regs.
__global__ __launch_bounds__(256, 3) void omp7_kernel(const float* __restrict__ xw,
                                                      const double* __restrict__ Dt,
                                                      const double* __restrict__ nrm2,
                                                      const double* __restrict__ G,
                                                      float* __restrict__ z_dl,
                                                      float* __restrict__ coeff,
                                                      double* __restrict__ partial) {
  __shared__ unsigned long long s_gk[4][8][16];   // [wave][8-lane group][si] 4 KiB
  __shared__ double s_al[SPAR][16];
  __shared__ int    s_sel[SPAR][16];
  __shared__ double s_red[4];

  const int tid  = threadIdx.x;
  const int w    = __builtin_amdgcn_readfirstlane(tid >> 6);
  const int lane = tid & 63;
  const int abase = (w << 7) | (lane << 1);        // this lane's 2 atoms
  const int bid = blockIdx.x;
  // XCD-friendly: both halves (h) of token l land on the same XCD (bid%8 fixed)
  const int x7 = bid & 7, h = (bid >> 3) & 1, q = bid >> 4;
  const int l  = (x7 << 7) | q;                    // 0..1023, bijective

  const float* xp = xw + (size_t)l * 2048 + (h << 4);   // + k*32, block-uniform

  double cor[2][16];
#pragma unroll
  for (int si = 0; si < 16; ++si) { cor[0][si] = 0.0; cor[1][si] = 0.0; }

  // ---- phase 1: cor[a][si] += Dt[k][abase+a] * x[k][h*16+si], 1-deep pipe ---
  const double* dbase = Dt + abase;
  double2 dcur = *(const double2*)dbase;
  float4 x0 = *(const float4*)xp;
  float4 x1 = *(const float4*)(xp + 4);
  float4 x2 = *(const float4*)(xp + 8);
  float4 x3 = *(const float4*)(xp + 12);
  for (int k = 0; k < MDIM; ++k) {
    double dv0 = dcur.x, dv1 = dcur.y;
    float4 y0 = x0, y1 = x1, y2 = x2, y3 = x3;
    if (k + 1 < MDIM) {
      dcur = *(const double2*)(dbase + (size_t)(k + 1) * NATOM);
      const float* xn = xp + (k + 1) * 32;
      x0 = *(const float4*)xn;       x1 = *(const float4*)(xn + 4);
      x2 = *(const float4*)(xn + 8); x3 = *(const float4*)(xn + 12);
    }
    double xv[16] = {(double)y0.x, (double)y0.y, (double)y0.z, (double)y0.w,
                     (double)y1.x, (double)y1.y, (double)y1.z, (double)y1.w,
                     (double)y2.x, (double)y2.y, (double)y2.z, (double)y2.w,
                     (double)y3.x, (double)y3.y, (double)y3.z, (double)y3.w};
#pragma unroll
    for (int si = 0; si < 16; ++si) {
      cor[0][si] += dv0 * xv[si];
      cor[1][si] += dv1 * xv[si];
    }
  }

  // ---- iterations ----
  unsigned int mk = 0xffffffffu;            // bit si: atom0 avail; bit 16+si: atom1

  for (int it = 0; it < SPAR; ++it) {
    // keypack + butterfly + publish, chunks of 4 si (limits live u64 regs)
#pragma unroll
    for (int cc = 0; cc < 4; ++cc) {
      unsigned long long key[4];
#pragma unroll
      for (int j = 0; j < 4; ++j) {
        const int si = cc * 4 + j;
        double c0 = cor[0][si], c1 = cor[1][si];
        bool v0 = (mk >> si) & 1u;
        bool v1 = (mk >> (16 + si)) & 1u;
        double a0 = v0 ? fabs(c0) : 0.0;
        double a1 = v1 ? fabs(c1) : 0.0;
        unsigned int h0 = v0 ? (unsigned int)__double2hiint(c0) : 0u;
        unsigned int h1 = v1 ? (unsigned int)__double2hiint(c1) : 0u;
        unsigned long long k0 = pack_key(a0, h0, abase);
        unsigned long long k1 = pack_key(a1, h1, abase + 1);
        key[j] = (k1 > k0) ? k1 : k0;
      }
#pragma unroll
      for (int o = 1; o < 8; o <<= 1) {
#pragma unroll
        for (int j = 0; j < 4; ++j) {
          unsigned long long ok2 = __shfl_xor(key[j], o);
          if (ok2 > key[j]) key[j] = ok2;
        }
      }
#pragma unroll
      for (int j = 0; j < 4; ++j) {
        const int si = cc * 4 + j;
        if ((lane & 7) == (si & 7)) s_gk[w][lane >> 3][si] = key[j];
      }
    }
    __syncthreads();                        // (A) keys published
    if (tid < 16) {                         // reducer: one thread per si
      unsigned long long kk = s_gk[0][0][tid];
#pragma unroll
      for (int ww = 0; ww < 4; ++ww)
#pragma unroll
        for (int g = 0; g < 8; ++g) {
          unsigned long long o = s_gk[ww][g][tid];
          if (o > kk) kk = o;
        }
      int gi = 511 - (int)(kk & 0x1FF);
      double c = __longlong_as_double((long long)(kk & ~0x3FFull));
      c = (kk & 0x200ull) ? -c : c;
      s_sel[it][tid] = gi;
      s_al[it][tid]  = c / (nrm2[gi] + EPS);
    }
    __syncthreads();                        // (B) winners published
    if (it != SPAR - 1) {
#pragma unroll
      for (int si = 0; si < 16; ++si) {
        int gi = s_sel[it][si];
        double alpha = s_al[it][si];
        int d = gi - abase;
        if ((unsigned)d < 2u) mk &= ~(1u << ((d << 4) + si));
        double2 g2 = *(const double2*)(G + (size_t)gi * NATOM + abase);
        cor[0][si] -= alpha * g2.x;
        cor[1][si] -= alpha * g2.y;
      }
    }
  }
  __syncthreads();                          // final s_sel/s_al visible to all

  // ---- epilogue A: z_dl + loss (s = tid&15, c = tid>>4 + r*16) ----
  const int s  = tid & 15;                  // sig within half-token
  const int b  = (h << 4) | s;              // sig within token
  double s2 = 0.0;
#pragma unroll
  for (int r = 0; r < 4; ++r) {
    int c = (tid >> 4) + (r << 4);
    double v = s_al[0][s] * Dt[(size_t)c * NATOM + s_sel[0][s]];
#pragma unroll
    for (int tt = 1; tt < SPAR; ++tt)
      v += s_al[tt][s] * Dt[(size_t)c * NATOM + s_sel[tt][s]];
    float zv = (float)v;
    z_dl[((size_t)b * MDIM + c) * 1024 + l] = zv;
    double x = (double)xw[(size_t)l * 2048 + (c << 5) + b];
    double diff = (double)zv - x;
    s2 += diff * diff;
  }
#pragma unroll
  for (int o = 32; o > 0; o >>= 1) s2 += __shfl_down(s2, o);
  if (lane == 0) s_red[w] = s2;
  __syncthreads();
  if (tid == 0) partial[bid] = ((s_red[0] + s_red[1]) + (s_red[2] + s_red[3]));

  // ---- epilogue B: coeff (thread = (sig s, 32-atom range g)) ----
  {
    int g = tid >> 4;                       // 0..15 -> atoms [g*32, g*32+32)
    int sl[SPAR]; float av[SPAR];
#pragma unroll
    for (int tt = 0; tt < SPAR; ++tt) {
      sl[tt] = s_sel[tt][s];
      av[tt] = (float)s_al[tt][s];
    }
    float* cp = coeff + (size_t)(g << 5) * NSIG + ((size_t)l << 5) + b;
#pragma unroll 8
    for (int j = 0; j < 32; ++j) {
      int a = (g << 5) + j;
      float v = 0.0f;
#pragma unroll
      for (int tt = 0; tt < SPAR; ++tt) v = (sl[tt] == a) ? av[tt] : v;
      cp[(size_t)j * NSIG] = v;
    }
  }
}

// ---------------- finalize loss ---------------------------------------------
__global__ __launch_bounds__(64) void finalize_kernel(const double* __restrict__ partial,
                                                      float* __restrict__ loss_out) {
  double s = 0.0;
  for (int i = threadIdx.x; i < 2048; i += 64) s += partial[i];
#pragma unroll
  for (int o = 32; o > 0; o >>= 1) s += __shfl_down(s, o);
  if (threadIdx.x == 0) loss_out[0] = (float)(1.25 * s / 2097152.0);
}

extern "C" void kernel_launch(void* const* d_in, const int* in_sizes, int n_in,
                              void* d_out, int out_size, void* d_ws, size_t ws_size,
                              hipStream_t stream) {
  const float* z_e = (const float*)d_in[0];
  const float* D   = (const float*)d_in[1];

  float* out      = (float*)d_out;
  float* z_dl     = out;                       // 2097152 elems
  float* loss_out = out + 2097152;             // 1 elem
  float* coeff    = out + 2097153;             // 512*32768 elems

  char*   ws      = (char*)d_ws;
  double* partial = (double*)ws;                                   // 16 KiB (2048)
  double* Dt      = (double*)(ws + 16384);                         // 256 KiB
  double* nrm2    = (double*)(ws + 16384 + 262144);                // 4 KiB
  double* G       = (double*)(ws + 16384 + 262144 + 4096);         // 2 MiB
  float*  xw      = (float*)(ws + 16384 + 262144 + 4096 + 2097152);// 8 MiB

  prep_kernel<<<1, 512, 0, stream>>>(D, Dt, nrm2);
  gram_kernel<<<NATOM, NATOM, 0, stream>>>(Dt, G);
  repack_kernel<<<1024, 512, 0, stream>>>(z_e, xw);
  omp7_kernel<<<2048, 256, 0, stream>>>(xw, Dt, nrm2, G, z_dl, coeff, partial);
  finalize_kernel<<<1, 64, 0, stream>>>(partial, loss_out);
}

// Round 8
// 159.508 us; speedup vs baseline: 1.2853x; 1.2853x over previous
//
#include <hip/hip_runtime.h>
#include <stdint.h>

#define NSIG   32768
#define NATOM  512
#define MDIM   64
#define SPAR   5
#define EPS    1e-10

// ---- prep: fp64 norms; Dt32 [dim][atom] f32; Dt64 [dim][atom] f64;
// ----       Dd64 [atom][dim] f64; rnrm = 1/(||d||^2+eps) f64
__global__ __launch_bounds__(512) void prep_kernel(const float* __restrict__ D,
                                                   float*  __restrict__ Dt32,
                                                   double* __restrict__ Dt64,
                                                   double* __restrict__ Dd64,
                                                   double* __restrict__ rnrm) {
  int n = threadIdx.x;                 // atom 0..511
  double ss = 0.0;
#pragma unroll 8
  for (int c = 0; c < MDIM; ++c) {
    double v = (double)D[c * NATOM + n];
    ss += v * v;
  }
  double norm = sqrt(ss);
  if (norm < 1e-10) norm = 1e-10;
  double s2 = 0.0;
#pragma unroll 8
  for (int c = 0; c < MDIM; ++c) {
    double v = (double)D[c * NATOM + n] / norm;
    Dt64[(size_t)c * NATOM + n] = v;
    Dd64[((size_t)n << 6) + c]  = v;
    Dt32[(size_t)c * NATOM + n] = (float)v;
    s2 += v * v;
  }
  rnrm[n] = 1.0 / (s2 + EPS);
}

// ---- Gram matrix in f32 (steers the f32 corr recursion only) ---------------
__global__ __launch_bounds__(512) void gram_kernel(const float* __restrict__ Dt32,
                                                   float* __restrict__ G32) {
  int i = blockIdx.x;
  int j = threadIdx.x;
  float s = 0.f;
#pragma unroll 8
  for (int c = 0; c < MDIM; ++c)
    s += Dt32[(size_t)c * NATOM + i] * Dt32[(size_t)c * NATOM + j];
  G32[(size_t)i * NATOM + j] = s;
}

// ---- repack: xw[l][c*32+b] = z_e[b][c][l] (f32) ----------------------------
__global__ __launch_bounds__(512) void repack_kernel(const float* __restrict__ z_e,
                                                     float* __restrict__ xw) {
  int bid = blockIdx.x;
  int l = ((bid & 7) << 7) | (bid >> 3);
#pragma unroll
  for (int p = 0; p < 4; ++p) {
    int idx = threadIdx.x + p * 512;       // 0..2047 = c*32+b
    xw[(size_t)l * 2048 + idx] =
      z_e[(size_t)(idx & 31) * 65536 + (size_t)(idx >> 5) * 1024 + l];
  }
}

// ---- main OMP kernel: fp32 GEMM/scan/Gram + fp64 candidate refinement -------
// block = 256 = 4 waves, 32 sigs/block (token l). Wave w owns sigs [8w,8w+8),
// covers all 512 atoms; lane owns atoms [lane*8, lane*8+8). cor[8][8] f32.
__global__ __launch_bounds__(256) void omp8_kernel(const float* __restrict__ xw,
                                                   const float* __restrict__ Dt32,
                                                   const double* __restrict__ Dt64,
                                                   const double* __restrict__ Dd64,
                                                   const double* __restrict__ rnrm,
                                                   const float* __restrict__ G32,
                                                   float* __restrict__ z_dl,
                                                   float* __restrict__ coeff,
                                                   double* __restrict__ partial) {
  __shared__ double r64[4][8][MDIM];       // 16 KiB fp64 residual [wave][si][dim]
  __shared__ double s_al[SPAR][32];
  __shared__ int    s_sel[SPAR][32];
  __shared__ double s_red[4];

  const int tid  = threadIdx.x;
  const int w    = __builtin_amdgcn_readfirstlane(tid >> 6);
  const int lane = tid & 63;
  const int abase = lane << 3;             // this lane's 8 atoms
  const int bid  = blockIdx.x;
  const int l    = ((bid & 7) << 7) | (bid >> 3);   // XCD swizzle (bijective)

  const float* xp = xw + (size_t)l * 2048 + (w << 3);   // + k*32 + si (uniform)

  // ---- stage fp64 residual r = x (wave-private; no barrier needed) ----
  {
    const int rsi = lane >> 3, rd0 = lane & 7;
#pragma unroll
    for (int j = 0; j < 8; ++j) {
      int d = rd0 + (j << 3);
      r64[w][rsi][d] = (double)xp[d * 32 + rsi];
    }
  }

  float cor[8][8];                         // [atom][sig] f32
#pragma unroll
  for (int a = 0; a < 8; ++a)
#pragma unroll
    for (int si = 0; si < 8; ++si) cor[a][si] = 0.0f;

  // ---- phase 1: f32 register GEMM, 1-deep pipelined ----
  const float* dbase = Dt32 + abase;
  float4 dA = *(const float4*)dbase;
  float4 dB = *(const float4*)(dbase + 4);
  float4 xA = *(const float4*)xp;
  float4 xB = *(const float4*)(xp + 4);
  for (int k = 0; k < MDIM; ++k) {
    float dv[8] = {dA.x, dA.y, dA.z, dA.w, dB.x, dB.y, dB.z, dB.w};
    float xv[8] = {xA.x, xA.y, xA.z, xA.w, xB.x, xB.y, xB.z, xB.w};
    if (k + 1 < MDIM) {
      const float* dn = dbase + (size_t)(k + 1) * NATOM;
      dA = *(const float4*)dn; dB = *(const float4*)(dn + 4);
      const float* xn = xp + (k + 1) * 32;
      xA = *(const float4*)xn; xB = *(const float4*)(xn + 4);
    }
#pragma unroll
    for (int a = 0; a < 8; ++a)
#pragma unroll
      for (int si = 0; si < 8; ++si)
        cor[a][si] += dv[a] * xv[si];
  }

  unsigned long long mk = ~0ull;           // availability bit (a*8+si)

#pragma unroll 1
  for (int it = 0; it < SPAR; ++it) {
    // ---- f32 scan: u32 keys (|c| truncated 10 bits, idx tiebreak) ----
    unsigned int kb[8];
#pragma unroll
    for (int si = 0; si < 8; ++si) {
      unsigned int best = 0;
#pragma unroll
      for (int a = 0; a < 8; ++a) {
        float ac = fabsf(cor[a][si]);
        unsigned int enc = (unsigned int)(511 - (abase + a));
        unsigned int kv = (__float_as_uint(ac) & 0xFFFFFC00u) | enc;
        bool avail = (mk >> ((a << 3) + si)) & 1ull;
        kv = avail ? kv : enc;             // masked competes as value 0 (np mask)
        best = best > kv ? best : kv;
      }
      kb[si] = best;
    }
    // stage A: max within 8-lane atom groups
#pragma unroll
    for (int o = 1; o < 8; o <<= 1)
#pragma unroll
      for (int si = 0; si < 8; ++si) {
        unsigned int ok = __shfl_xor(kb[si], o);
        kb[si] = kb[si] > ok ? kb[si] : ok;
      }
    // stage B: lane takes si = lane&7, max across groups
    unsigned int kk = kb[0];
#pragma unroll
    for (int si = 1; si < 8; ++si) kk = ((lane & 7) == si) ? kb[si] : kk;
#pragma unroll
    for (int o = 8; o < 64; o <<= 1) {
      unsigned int ok = __shfl_xor(kk, o);
      kk = kk > ok ? kk : ok;
    }
    unsigned int wkey[8];
#pragma unroll
    for (int si = 0; si < 8; ++si) wkey[si] = __shfl(kk, si);

    // ---- per-si: fp64 refinement of candidates within 0.1% band ----
#pragma unroll
    for (int si = 0; si < 8; ++si) {
      unsigned int wk = wkey[si];
      int widx = 511 - (int)(wk & 0x1FFu);
      float mabs = __uint_as_float(wk & 0xFFFFFC00u);
      float thr = mabs * 0.999f;
      int bestg = widx;
      double bestc = 0.0;
      unsigned long long bestk = 0ull;
      bool any = false;
#pragma unroll
      for (int a = 0; a < 8; ++a) {
        float ac = fabsf(cor[a][si]);
        bool avail = (mk >> ((a << 3) + si)) & 1ull;
        bool pred = avail && (mabs > 0.0f) && (ac >= thr);
        unsigned long long bal = __ballot(pred);
        while (bal) {                      // wave-uniform loop (usually 1 iter)
          int src = __ffsll(bal) - 1;
          bal &= bal - 1;
          int gi = (src << 3) + a;
          // exact np formula: corr = d_gi . r  (fp64, deterministic order)
          double p = Dd64[((size_t)gi << 6) + lane] * r64[w][si][lane];
#pragma unroll
          for (int o = 1; o < 64; o <<= 1) p += __shfl_xor(p, o);
          unsigned long long k64 =
            ((unsigned long long)__double_as_longlong(fabs(p)) & ~0x3FFull)
            | (unsigned long long)(511 - gi);
          if (!any || k64 > bestk) { bestk = k64; bestc = p; bestg = gi; any = true; }
        }
      }
      if (!any) {                          // degenerate all-zero band
        double p = Dd64[((size_t)bestg << 6) + lane] * r64[w][si][lane];
#pragma unroll
        for (int o = 1; o < 64; o <<= 1) p += __shfl_xor(p, o);
        bestc = p;
      }
      double alpha = bestc * rnrm[bestg];
      int d = bestg - abase;
      if ((unsigned)d < 8u) mk &= ~(1ull << ((d << 3) + si));
      if (lane == 0) {
        s_sel[it][(w << 3) + si] = bestg;
        s_al[it][(w << 3) + si]  = alpha;
      }
      if (it != SPAR - 1) {
        // fp64 residual update (1 dim/lane) + f32 Gram recursion
        r64[w][si][lane] -= alpha * Dd64[((size_t)bestg << 6) + lane];
        float af = (float)alpha;
        const float* gp = G32 + (size_t)bestg * NATOM + abase;
        float4 g0 = *(const float4*)gp;
        float4 g1 = *(const float4*)(gp + 4);
        cor[0][si] -= af * g0.x; cor[1][si] -= af * g0.y;
        cor[2][si] -= af * g0.z; cor[3][si] -= af * g0.w;
        cor[4][si] -= af * g1.x; cor[5][si] -= af * g1.y;
        cor[6][si] -= af * g1.z; cor[7][si] -= af * g1.w;
      }
    }
  }
  __syncthreads();                         // publish s_sel/s_al to all waves

  // ---- epilogue A: z_dl (fp64) + loss ----
  const int s = tid & 31;
  {
    const int c0 = tid >> 5;               // 0..7
    double s2 = 0.0;
#pragma unroll
    for (int r = 0; r < 8; ++r) {
      int c = c0 + (r << 3);
      double v = s_al[0][s] * Dt64[(size_t)c * NATOM + s_sel[0][s]];
#pragma unroll
      for (int tt = 1; tt < SPAR; ++tt)
        v += s_al[tt][s] * Dt64[(size_t)c * NATOM + s_sel[tt][s]];
      float zv = (float)v;
      z_dl[((size_t)s * MDIM + c) * 1024 + l] = zv;
      double x = (double)xw[(size_t)l * 2048 + (c << 5) + s];
      double diff = (double)zv - x;
      s2 += diff * diff;
    }
#pragma unroll
    for (int o = 32; o > 0; o >>= 1) s2 += __shfl_down(s2, o);
    if (lane == 0) s_red[w] = s2;
  }
  __syncthreads();
  if (tid == 0) partial[bid] = (s_red[0] + s_red[1]) + (s_red[2] + s_red[3]);

  // ---- epilogue B: coeff = zero-fill + sparse scatter ----
  {
    const float4 z4 = make_float4(0.f, 0.f, 0.f, 0.f);
#pragma unroll
    for (int p = 0; p < 16; ++p) {
      int idx = tid + (p << 8);            // 0..4095 = atom*8 + quad
      int a = idx >> 3, q = idx & 7;
      *(float4*)(coeff + (size_t)a * NSIG + ((size_t)l << 5) + (q << 2)) = z4;
    }
  }
  __syncthreads();                         // order zeros before scatter (same L2)
  if (tid < 32) {
#pragma unroll
    for (int tt = 0; tt < SPAR; ++tt) {
      int gi = s_sel[tt][tid];
      coeff[(size_t)gi * NSIG + ((size_t)l << 5) + tid] = (float)s_al[tt][tid];
    }
  }
}

// ---- finalize loss ---------------------------------------------------------
__global__ __launch_bounds__(64) void finalize_kernel(const double* __restrict__ partial,
                                                      float* __restrict__ loss_out) {
  double s = 0.0;
  for (int i = threadIdx.x; i < 1024; i += 64) s += partial[i];
#pragma unroll
  for (int o = 32; o > 0; o >>= 1) s += __shfl_down(s, o);
  if (threadIdx.x == 0) loss_out[0] = (float)(1.25 * s / 2097152.0);
}

extern "C" void kernel_launch(void* const* d_in, const int* in_sizes, int n_in,
                              void* d_out, int out_size, void* d_ws, size_t ws_size,
                              hipStream_t stream) {
  const float* z_e = (const float*)d_in[0];
  const float* D   = (const float*)d_in[1];

  float* out      = (float*)d_out;
  float* z_dl     = out;                       // 2097152 elems
  float* loss_out = out + 2097152;             // 1 elem
  float* coeff    = out + 2097153;             // 512*32768 elems

  char*   ws      = (char*)d_ws;
  double* partial = (double*)ws;                               // 8 KiB (1024)
  float*  Dt32    = (float*) (ws + 8192);                      // 128 KiB
  double* Dt64    = (double*)(ws + 8192 + 131072);             // 256 KiB
  double* Dd64    = (double*)(ws + 8192 + 131072 + 262144);    // 256 KiB
  double* rnrm    = (double*)(ws + 8192 + 131072 + 524288);    // 4 KiB
  float*  G32     = (float*) (ws + 8192 + 131072 + 524288 + 4096);           // 1 MiB
  float*  xw      = (float*) (ws + 8192 + 131072 + 524288 + 4096 + 1048576); // 8 MiB
  // total ~= 10.1 MB (< the >=10.47 MB workspace proven available in R6)

  prep_kernel<<<1, 512, 0, stream>>>(D, Dt32, Dt64, Dd64, rnrm);
  gram_kernel<<<NATOM, NATOM, 0, stream>>>(Dt32, G32);
  repack_kernel<<<1024, 512, 0, stream>>>(z_e, xw);
  omp8_kernel<<<1024, 256, 0, stream>>>(xw, Dt32, Dt64, Dd64, rnrm, G32,
                                        z_dl, coeff, partial);
  finalize_kernel<<<1, 64, 0, stream>>>(partial, loss_out);
}